// Round 7
// baseline (431.059 us; speedup 1.0000x reference)
//
#include <hip/hip_runtime.h>
#include <math.h>

#define T_LEN 4096
#define C_CH 64
#define B_N 64
#define NBINS 2049   // T/2 + 1
#define APITCH 2052  // amps_part row pitch (16B-aligned)
#define K2 6         // 2*TOP_K
#define TOPK 3
#define THRESH_V 0.2f

// LDS pad: one extra float2 per 32 -> breaks power-of-2 stride bank aliasing
#define PIDX(i) ((i) + ((i) >> 5))
#define ZSZ (T_LEN + (T_LEN >> 5))

__device__ __forceinline__ unsigned short f2bf(float v) {
    unsigned int u = __float_as_uint(v);
    u += 0x7FFFu + ((u >> 16) & 1u);  // RNE
    return (unsigned short)(u >> 16);
}
__device__ __forceinline__ float bf2f(unsigned short h) {
    return __uint_as_float(((unsigned int)h) << 16);
}

// ---------------- complex helpers ----------------
__device__ __forceinline__ float2 cmul(float2 a, float2 b) {
    return make_float2(a.x * b.x - a.y * b.y, a.x * b.y + a.y * b.x);
}
__device__ __forceinline__ float2 cadd(float2 a, float2 b) { return make_float2(a.x + b.x, a.y + b.y); }
__device__ __forceinline__ float2 csub(float2 a, float2 b) { return make_float2(a.x - b.x, a.y - b.y); }

// 16-point forward DFT in registers (natural in, natural out), radix-2 DIT.
__device__ __forceinline__ void dft16(float2* v) {
    const float C2 = 0.70710678118654752f;
    const float C1 = 0.92387953251128676f;
    const float S1 = 0.38268343236508977f;
    const int br[16] = {0, 8, 4, 12, 2, 10, 6, 14, 1, 9, 5, 13, 3, 11, 7, 15};
    float2 a[16];
#pragma unroll
    for (int i = 0; i < 16; ++i) a[i] = v[br[i]];
#pragma unroll
    for (int g = 0; g < 16; g += 2) {
        float2 t = a[g + 1];
        a[g + 1] = csub(a[g], t);
        a[g] = cadd(a[g], t);
    }
#pragma unroll
    for (int g = 0; g < 16; g += 4) {
        {
            float2 t = a[g + 2];
            a[g + 2] = csub(a[g], t);
            a[g] = cadd(a[g], t);
        }
        {
            float2 t = make_float2(a[g + 3].y, -a[g + 3].x);  // -i * z
            a[g + 3] = csub(a[g + 1], t);
            a[g + 1] = cadd(a[g + 1], t);
        }
    }
    {
        const float2 W4[4] = {{1.f, 0.f}, {C2, -C2}, {0.f, -1.f}, {-C2, -C2}};
#pragma unroll
        for (int g = 0; g < 16; g += 8)
#pragma unroll
            for (int j = 0; j < 4; ++j) {
                float2 t = cmul(W4[j], a[g + 4 + j]);
                a[g + 4 + j] = csub(a[g + j], t);
                a[g + j] = cadd(a[g + j], t);
            }
    }
    {
        const float2 W8[8] = {{1.f, 0.f}, {C1, -S1}, {C2, -C2}, {S1, -C1},
                              {0.f, -1.f}, {-S1, -C1}, {-C2, -C2}, {-C1, -S1}};
#pragma unroll
        for (int j = 0; j < 8; ++j) {
            float2 t = cmul(W8[j], a[8 + j]);
            a[8 + j] = csub(a[j], t);
            a[j] = cadd(a[j], t);
        }
    }
#pragma unroll
    for (int i = 0; i < 16; ++i) v[i] = a[i];
}

// ---------------- shared top-6 device helper (lax.top_k tie semantics) ----------------
__device__ __forceinline__ void topk_select(float* vals, float* sval, int* sidx, int* sel,
                                            int b, int tid, int* p_int, int* preval) {
    for (int pass = 0; pass < K2; ++pass) {
        float bv = -INFINITY;
        int bi = NBINS;
        for (int k = tid; k < NBINS; k += 256) {
            float v = vals[k];
            if (v > bv || (v == bv && k < bi)) { bv = v; bi = k; }
        }
        sval[tid] = bv;
        sidx[tid] = bi;
        __syncthreads();
        for (int off = 128; off > 0; off >>= 1) {
            if (tid < off) {
                float ov = sval[tid + off];
                int oi = sidx[tid + off];
                if (ov > sval[tid] || (ov == sval[tid] && oi < sidx[tid])) {
                    sval[tid] = ov;
                    sidx[tid] = oi;
                }
            }
            __syncthreads();
        }
        if (tid == 0) {
            sel[pass] = sidx[0];
            vals[sidx[0]] = -INFINITY;
        }
        __syncthreads();
    }
    if (tid < K2) {
        int idx = sel[tid];
        float pf = (float)T_LEN / (float)(idx + 1);
        int ir = (pf >= 2.0f) && (pf <= (float)(T_LEN / 2));
        float pff = floorf(pf);
        int iri = (pff >= 2.0f) && (pff <= (float)(T_LEN / 2));
        int pi = (int)pff;
        pi = pi < 2 ? 2 : (pi > T_LEN / 2 ? T_LEN / 2 : pi);
        p_int[b * K2 + tid] = pi;
        preval[b * K2 + tid] = ir && iri;
    }
}

// ---------------- K0: transpose x[B,T,C] fp32 -> xtbf[B,C,T] bf16 (+zero counters) ----
__global__ void transpose_cvt_kernel(const float* __restrict__ x,
                                     unsigned short* __restrict__ xtbf,
                                     int* __restrict__ cnts) {
    __shared__ float tile[64][65];
    const int b = blockIdx.y;
    const int t0 = blockIdx.x * 64;
    const int lane = threadIdx.x & 63;
    const int w = threadIdx.x >> 6;  // 0..3
    if (blockIdx.x == 0 && blockIdx.y == 0 && threadIdx.x < B_N + 1)
        cnts[threadIdx.x] = 0;  // 64 per-b fft counters + 1 score counter
    const float* xb = x + (size_t)b * T_LEN * C_CH;
#pragma unroll
    for (int i = 0; i < 16; ++i) {
        int r = w * 16 + i;  // t within tile
        tile[r][lane] = xb[(size_t)(t0 + r) * C_CH + lane];
    }
    __syncthreads();
    const int half = lane >> 5;     // 0..1
    const int tc = (lane & 31) * 2; // t-pair within tile
#pragma unroll
    for (int it = 0; it < 8; ++it) {
        int c = it * 8 + w * 2 + half;
        float v0 = tile[tc][c];
        float v1 = tile[tc + 1][c];
        unsigned int o = (unsigned int)f2bf(v0) | ((unsigned int)f2bf(v1) << 16);
        unsigned int* dst = (unsigned int*)(xtbf + ((size_t)b * C_CH + c) * T_LEN + t0);
        dst[lane & 31] = o;
    }
}

// ---------------- K1: radix-16 4096-pt complex FFT + partial amps; last block/b: topk --
// MODE 0: bf16 xtbf[B,C,T], partial writes + fused topk. MODE 1: fp32 x[B,T,C] strided,
// atomicAdd into amps[b*NBINS+k] (fallback; standalone topk kernel follows).
template <int MODE>
__global__ void fft_amp_kernel(const void* __restrict__ srcv, float* __restrict__ apart,
                               int* __restrict__ cnts, int* __restrict__ p_int,
                               int* __restrict__ preval) {
    __shared__ float2 Z[ZSZ];  // ~33 KB padded
    __shared__ int lastflag;
    const int pair = blockIdx.x;  // 0..31
    const int b = blockIdx.y;
    const int tid = threadIdx.x;

    if (MODE == 0) {
        const unsigned short* r0 =
            (const unsigned short*)srcv + ((size_t)b * C_CH + pair * 2) * T_LEN;
        const unsigned short* r1 = r0 + T_LEN;
#pragma unroll
        for (int k = 0; k < 2; ++k) {
            int t0 = k * 2048 + tid * 8;
            uint4 u0 = *(const uint4*)(r0 + t0);
            uint4 u1 = *(const uint4*)(r1 + t0);
            unsigned int a[4] = {u0.x, u0.y, u0.z, u0.w};
            unsigned int c[4] = {u1.x, u1.y, u1.z, u1.w};
#pragma unroll
            for (int j = 0; j < 4; ++j) {
                Z[PIDX(t0 + 2 * j)] = make_float2(__uint_as_float(a[j] << 16),
                                                  __uint_as_float(c[j] << 16));
                Z[PIDX(t0 + 2 * j + 1)] = make_float2(__uint_as_float(a[j] & 0xFFFF0000u),
                                                      __uint_as_float(c[j] & 0xFFFF0000u));
            }
        }
    } else {
        const float* x = (const float*)srcv;
        const int c0 = pair * 2;
        for (int t = tid; t < T_LEN; t += 256)
            Z[PIDX(t)] = *(const float2*)(x + ((size_t)b * T_LEN + t) * C_CH + c0);
    }
    __syncthreads();

    // ---- stage 0: n1 = tid; DFT16 over n2, twiddle w4096^(n1 r); in-place per-thread
    {
        float2 v[16];
#pragma unroll
        for (int t = 0; t < 16; ++t) v[t] = Z[PIDX(tid + 256 * t)];
        dft16(v);
        float s, c;
        __sincosf(-(float)tid * 1.5339807878856412e-3f, &s, &c);  // -2pi/4096 * n1
        float2 w1 = make_float2(c, s), w = w1;
#pragma unroll
        for (int r = 1; r < 16; ++r) {
            v[r] = cmul(v[r], w);
            w = cmul(w, w1);
        }
#pragma unroll
        for (int r = 0; r < 16; ++r) Z[PIDX(256 * r + tid)] = v[r];
    }
    __syncthreads();

    // ---- stage 1: thread (r,mu); DFT16 over nu; twiddle w256^(mu rho); in-place.
    {
        const int r = tid >> 4, mu = tid & 15;
        float2 v[16];
#pragma unroll
        for (int nu = 0; nu < 16; ++nu) v[nu] = Z[PIDX(256 * r + mu + 16 * nu)];
        dft16(v);
        float s, c;
        __sincosf(-(float)mu * 2.4543692606170259e-2f, &s, &c);  // -2pi/256 * mu
        float2 w1 = make_float2(c, s), w = w1;
#pragma unroll
        for (int rho = 1; rho < 16; ++rho) {
            v[rho] = cmul(v[rho], w);
            w = cmul(w, w1);
        }
#pragma unroll
        for (int rho = 0; rho < 16; ++rho) Z[PIDX(256 * r + mu + 16 * rho)] = v[rho];
    }
    // stage1->stage2 exchange is within a 16-thread r-group (wave-local, DS in-order)
    __builtin_amdgcn_wave_barrier();

    // ---- stage 2: thread (r,rho); DFT16 over mu; in-place per-thread
    {
        const int r = tid >> 4, rho = tid & 15;
        float2 v[16];
#pragma unroll
        for (int mu = 0; mu < 16; ++mu) v[mu] = Z[PIDX(256 * r + mu + 16 * rho)];
        dft16(v);
#pragma unroll
        for (int mp = 0; mp < 16; ++mp) Z[PIDX(256 * r + mp + 16 * rho)] = v[mp];
    }
    __syncthreads();

    // ---- Hermitian unpack; X[k] at s(k) = 256*(k&15) + 16*((k>>4)&15) + (k>>8)
    float* mypart = apart + ((size_t)b * 32 + pair) * APITCH;
    for (int k = tid; k < NBINS; k += 256) {
        int km = (T_LEN - k) & (T_LEN - 1);
        int sk = 256 * (k & 15) + 16 * ((k >> 4) & 15) + (k >> 8);
        int sm = 256 * (km & 15) + 16 * ((km >> 4) & 15) + (km >> 8);
        float2 zk = Z[PIDX(sk)];
        float2 zm = Z[PIDX(sm)];
        float ax = 0.5f * (zk.x + zm.x);
        float ay = 0.5f * (zk.y - zm.y);
        float bx = 0.5f * (zk.y + zm.y);
        float by = -0.5f * (zk.x - zm.x);
        float amp = sqrtf(ax * ax + ay * ay) + sqrtf(bx * bx + by * by);
        if (MODE == 0)
            mypart[k] = amp;
        else
            atomicAdd(&apart[(size_t)b * NBINS + k], amp);
    }

    if (MODE != 0) return;

    // ---- fused per-b topk: last of the 32 blocks sums partials and selects top-6 ----
    __threadfence();  // release: my partials visible device-wide
    if (tid == 0) lastflag = (atomicAdd(&cnts[b], 1) == 31) ? 1 : 0;
    __syncthreads();  // also guards Z reuse below
    if (!lastflag) return;
    __threadfence();  // acquire: all 32 blocks' partials visible

    float* vals = (float*)Z;          // 2049 floats (reuse FFT LDS)
    float* sval = vals + NBINS;       // 256
    int* sidx = (int*)(sval + 256);   // 256
    int* sel = sidx + 256;            // K2
    const float* bp = apart + (size_t)b * 32 * APITCH;
    for (int k = tid; k < NBINS; k += 256) {
        float s = 0.f;
        for (int p2 = 0; p2 < 32; ++p2) s += bp[(size_t)p2 * APITCH + k];
        vals[k] = s;
    }
    __syncthreads();
    topk_select(vals, sval, sidx, sel, b, tid, p_int, preval);
}

// ---------------- K2: standalone topk (fallback path only) ----------------
__global__ void topk_kernel(const float* __restrict__ amps, int* __restrict__ p_int,
                            int* __restrict__ preval) {
    __shared__ float vals[NBINS];
    __shared__ float sval[256];
    __shared__ int sidx[256];
    __shared__ int sel[K2];
    const int b = blockIdx.x;
    const int tid = threadIdx.x;
    for (int k = tid; k < NBINS; k += 256) vals[k] = amps[(size_t)b * NBINS + k];
    __syncthreads();
    topk_select(vals, sval, sidx, sel, b, tid, p_int, preval);
}

// ---------------- K3a: r[t],q[t] from xtbf[B,C,T] — thread per t, batched loads -------
__global__ void rq_kernel(const unsigned short* __restrict__ xtbf,
                          const int* __restrict__ p_int, float* __restrict__ r_ws,
                          float* __restrict__ q_ws) {
    const int b = blockIdx.y;
    const int t = blockIdx.x * 64 + threadIdx.x;
    const unsigned short* xb = xtbf + (size_t)b * C_CH * T_LEN;

    int tpc[K2];
    float m[K2];
#pragma unroll
    for (int j = 0; j < K2; ++j) {
        int tp = t + p_int[b * K2 + j];  // wave-uniform p -> scalar load
        m[j] = (tp < T_LEN) ? 1.f : 0.f;
        tpc[j] = (tp < T_LEN) ? tp : (T_LEN - 1);
    }

    float qacc = 0.f;
    float racc[K2] = {0.f, 0.f, 0.f, 0.f, 0.f, 0.f};
    for (int cc = 0; cc < C_CH; cc += 8) {
        float a[8];
        float bv[K2][8];
#pragma unroll
        for (int k = 0; k < 8; ++k) a[k] = bf2f(xb[(size_t)(cc + k) * T_LEN + t]);
#pragma unroll
        for (int j = 0; j < K2; ++j)
#pragma unroll
            for (int k = 0; k < 8; ++k)
                bv[j][k] = bf2f(xb[(size_t)(cc + k) * T_LEN + tpc[j]]);
#pragma unroll
        for (int k = 0; k < 8; ++k) {
            qacc += a[k] * a[k];
#pragma unroll
            for (int j = 0; j < K2; ++j) racc[j] += a[k] * bv[j][k];
        }
    }
    q_ws[(size_t)b * T_LEN + t] = qacc;
#pragma unroll
    for (int j = 0; j < K2; ++j)
        r_ws[((size_t)b * K2 + j) * T_LEN + t] = racc[j] * m[j];
}

// ---------------- shared scan helper ----------------
__device__ __forceinline__ void block_scan_4096(float* a, float* tsum, int tid) {
    float loc[16];
    const int base = tid * 16;
    float s = 0.f;
#pragma unroll
    for (int i = 0; i < 16; ++i) {
        s += a[base + i];
        loc[i] = s;
    }
    tsum[tid] = s;
    __syncthreads();
    for (int off = 1; off < 256; off <<= 1) {
        float v = (tid >= off) ? tsum[tid - off] : 0.f;
        __syncthreads();
        tsum[tid] += v;
        __syncthreads();
    }
    float offs = tsum[tid] - s;
#pragma unroll
    for (int i = 0; i < 16; ++i) a[base + i] = offs + loc[i];
    __syncthreads();
}

// ---------------- device select (shared by fused + standalone paths) ----------------
__device__ __forceinline__ void do_select(int b, const int* p_int, const int* preval,
                                          const float* scores, float* out) {
    int sel[TOPK];
    int cnt = 0;
    for (int j = 0; j < K2; ++j) {
        if (preval[b * K2 + j] && scores[b * K2 + j] > THRESH_V) {
            if (cnt < TOPK) sel[cnt] = p_int[b * K2 + j];
            cnt++;
        }
    }
    if (cnt > TOPK) cnt = TOPK;
    int add[4];
    int nadd = 0;
    int cms[4] = {T_LEN / 4, T_LEN / 3, T_LEN / 2, (int)((float)T_LEN / 1.5f)};
    for (int i = 0; i < 4; ++i)
        if (cms[i] >= 2 && cms[i] <= T_LEN / 2) add[nadd++] = cms[i];
    for (int j = 0; j < TOPK; ++j) {
        float pv, wv;
        if (j < cnt) {
            pv = (float)sel[j];
            wv = 1.0f;
        } else {
            int a = j - cnt;
            if (a > nadd - 1) a = nadd - 1;
            pv = (float)add[a];
            wv = 0.5f;
        }
        out[b * TOPK + j] = pv;
        out[B_N * TOPK + b * TOPK + j] = wv;
    }
}

// ---------------- K3b: scan + segment cosines; last block also does the select -------
__global__ void score_kernel(const float* __restrict__ r_ws, const float* __restrict__ q_ws,
                             const int* __restrict__ p_int, const int* __restrict__ preval,
                             float* __restrict__ scores, int* __restrict__ counter,
                             float* __restrict__ out) {
    __shared__ float r_s[T_LEN];
    __shared__ float q_s[T_LEN];
    __shared__ float tsum[256];
    __shared__ int lastflag;
    const int cand = blockIdx.x;
    const int b = blockIdx.y;
    const int tid = threadIdx.x;
    const int p = p_int[b * K2 + cand];
    const float4* rsrc = (const float4*)(r_ws + ((size_t)b * K2 + cand) * T_LEN);
    const float4* qsrc = (const float4*)(q_ws + (size_t)b * T_LEN);
    for (int i = tid; i < T_LEN / 4; i += 256) {
        ((float4*)r_s)[i] = rsrc[i];
        ((float4*)q_s)[i] = qsrc[i];
    }
    __syncthreads();
    block_scan_4096(r_s, tsum, tid);
    block_scan_4096(q_s, tsum, tid);
    const int nper = T_LEN / p;
    float part = 0.f;
    for (int i = tid; i < nper - 1; i += 256) {
        int s0 = i * p;
        int e = s0 + p;
        int e2 = e + p;
        float crs = s0 ? r_s[s0 - 1] : 0.f;
        float dots = r_s[e - 1] - crs;
        float cqs = s0 ? q_s[s0 - 1] : 0.f;
        float qa = q_s[e - 1] - cqs;
        float qb = q_s[e2 - 1] - q_s[e - 1];
        float na = sqrtf(fmaxf(qa, 0.f));
        float nb = sqrtf(fmaxf(qb, 0.f));
        part += dots / fmaxf(na * nb, 1e-8f);
    }
    tsum[tid] = part;
    __syncthreads();
    for (int off = 128; off > 0; off >>= 1) {
        if (tid < off) tsum[tid] += tsum[tid + off];
        __syncthreads();
    }
    if (tid == 0) {
        scores[b * K2 + cand] = tsum[0] / (float)(nper - 1);
        __threadfence();
        int old = atomicAdd(counter, 1);
        lastflag = (old == K2 * B_N - 1) ? 1 : 0;
    }
    __syncthreads();
    if (lastflag && tid < B_N) {
        __threadfence();
        do_select(tid, p_int, preval, scores, out);
    }
}

// ---------------- fallback fused autocorr (tiny-ws path) ----------------
__global__ void autocorr_kernel(const float* __restrict__ x, const int* __restrict__ p_int,
                                float* __restrict__ scores) {
    __shared__ float r_s[T_LEN];
    __shared__ float q_s[T_LEN];
    __shared__ float tsum[256];
    const int cand = blockIdx.x;
    const int b = blockIdx.y;
    const int tid = threadIdx.x;
    const int p = p_int[b * K2 + cand];
    const float* xb = x + (size_t)b * T_LEN * C_CH;
    for (int t = tid; t < T_LEN; t += 256) {
        const float4* row = (const float4*)(xb + (size_t)t * C_CH);
        float q = 0.f, r = 0.f;
        if (t + p < T_LEN) {
            const float4* row2 = (const float4*)(xb + (size_t)(t + p) * C_CH);
#pragma unroll
            for (int i = 0; i < 16; ++i) {
                float4 a = row[i], c = row2[i];
                r += a.x * c.x + a.y * c.y + a.z * c.z + a.w * c.w;
                q += a.x * a.x + a.y * a.y + a.z * a.z + a.w * a.w;
            }
        } else {
#pragma unroll
            for (int i = 0; i < 16; ++i) {
                float4 a = row[i];
                q += a.x * a.x + a.y * a.y + a.z * a.z + a.w * a.w;
            }
        }
        r_s[t] = r;
        q_s[t] = q;
    }
    __syncthreads();
    block_scan_4096(r_s, tsum, tid);
    block_scan_4096(q_s, tsum, tid);
    const int nper = T_LEN / p;
    float part = 0.f;
    for (int i = tid; i < nper - 1; i += 256) {
        int s0 = i * p;
        int e = s0 + p;
        int e2 = e + p;
        float crs = s0 ? r_s[s0 - 1] : 0.f;
        float dots = r_s[e - 1] - crs;
        float cqs = s0 ? q_s[s0 - 1] : 0.f;
        float qa = q_s[e - 1] - cqs;
        float qb = q_s[e2 - 1] - q_s[e - 1];
        float na = sqrtf(fmaxf(qa, 0.f));
        float nb = sqrtf(fmaxf(qb, 0.f));
        part += dots / fmaxf(na * nb, 1e-8f);
    }
    tsum[tid] = part;
    __syncthreads();
    for (int off = 128; off > 0; off >>= 1) {
        if (tid < off) tsum[tid] += tsum[tid + off];
        __syncthreads();
    }
    if (tid == 0) scores[b * K2 + cand] = tsum[0] / (float)(nper - 1);
}

// ---------------- K4: standalone select (fallback path only) ----------------
__global__ void select_kernel(const int* __restrict__ p_int, const int* __restrict__ preval,
                              const float* __restrict__ scores, float* __restrict__ out) {
    const int b = threadIdx.x;
    if (b >= B_N) return;
    do_select(b, p_int, preval, scores, out);
}

static size_t align256(size_t v) { return (v + 255) & ~(size_t)255; }

extern "C" void kernel_launch(void* const* d_in, const int* in_sizes, int n_in,
                              void* d_out, int out_size, void* d_ws, size_t ws_size,
                              hipStream_t stream) {
    const float* x = (const float*)d_in[0];
    float* out = (float*)d_out;
    char* ws = (char*)d_ws;

    const size_t cnt_b = 256;                                                    // 65 ints
    const size_t int_b = align256((size_t)B_N * K2 * sizeof(int));
    const size_t apart_b = align256((size_t)B_N * 32 * APITCH * sizeof(float));  // 16.8 MB
    const size_t r_b = align256((size_t)B_N * K2 * T_LEN * sizeof(float));       // 6.3 MB
    const size_t q_b = align256((size_t)B_N * T_LEN * sizeof(float));            // 1 MB
    const size_t xtbf_b = align256((size_t)B_N * T_LEN * C_CH * sizeof(short));  // 32 MB

    size_t off = 0;
    int* cnts = (int*)(ws + off); off += cnt_b;
    int* p_int = (int*)(ws + off); off += int_b;
    int* preval = (int*)(ws + off); off += int_b;
    float* scores = (float*)(ws + off); off += int_b;
    float* apart = (float*)(ws + off); off += apart_b;
    float* r_ws = (float*)(ws + off); off += r_b;
    float* q_ws = (float*)(ws + off); off += q_b;
    unsigned short* xtbf = (unsigned short*)(ws + off); off += xtbf_b;
    const size_t full_need = off;

    if (ws_size >= full_need) {
        // 4 graph nodes, no memsets: transpose(+zero cnts) -> fft(+topk) -> rq -> score(+select)
        transpose_cvt_kernel<<<dim3(T_LEN / 64, B_N), 256, 0, stream>>>(x, xtbf, cnts);
        fft_amp_kernel<0><<<dim3(32, B_N), 256, 0, stream>>>(xtbf, apart, cnts, p_int, preval);
        rq_kernel<<<dim3(T_LEN / 64, B_N), 64, 0, stream>>>(xtbf, p_int, r_ws, q_ws);
        score_kernel<<<dim3(K2, B_N), 256, 0, stream>>>(r_ws, q_ws, p_int, preval, scores,
                                                        &cnts[B_N], out);
    } else {
        // tiny-ws fallback: amps lives at apart, zeroed; classic 5-kernel chain
        hipMemsetAsync(apart, 0, (size_t)B_N * NBINS * sizeof(float), stream);
        fft_amp_kernel<1><<<dim3(32, B_N), 256, 0, stream>>>(x, apart, cnts, p_int, preval);
        topk_kernel<<<B_N, 256, 0, stream>>>(apart, p_int, preval);
        autocorr_kernel<<<dim3(K2, B_N), 256, 0, stream>>>(x, p_int, scores);
        select_kernel<<<1, 64, 0, stream>>>(p_int, preval, scores, out);
    }
}

// Round 8
// 168.500 us; speedup vs baseline: 2.5582x; 2.5582x over previous
//
#include <hip/hip_runtime.h>
#include <math.h>

#define T_LEN 4096
#define C_CH 64
#define B_N 64
#define NBINS 2049   // T/2 + 1
#define K2 6         // 2*TOP_K
#define TOPK 3
#define THRESH_V 0.2f

// LDS pad: one extra float2 per 32 -> breaks power-of-2 stride bank aliasing
#define PIDX(i) ((i) + ((i) >> 5))
#define ZSZ (T_LEN + (T_LEN >> 5))

__device__ __forceinline__ unsigned short f2bf(float v) {
    unsigned int u = __float_as_uint(v);
    u += 0x7FFFu + ((u >> 16) & 1u);  // RNE
    return (unsigned short)(u >> 16);
}
__device__ __forceinline__ float bf2f(unsigned short h) {
    return __uint_as_float(((unsigned int)h) << 16);
}

// ---------------- complex helpers ----------------
__device__ __forceinline__ float2 cmul(float2 a, float2 b) {
    return make_float2(a.x * b.x - a.y * b.y, a.x * b.y + a.y * b.x);
}
__device__ __forceinline__ float2 cadd(float2 a, float2 b) { return make_float2(a.x + b.x, a.y + b.y); }
__device__ __forceinline__ float2 csub(float2 a, float2 b) { return make_float2(a.x - b.x, a.y - b.y); }

// 16-point forward DFT in registers (natural in, natural out), radix-2 DIT.
__device__ __forceinline__ void dft16(float2* v) {
    const float C2 = 0.70710678118654752f;
    const float C1 = 0.92387953251128676f;
    const float S1 = 0.38268343236508977f;
    const int br[16] = {0, 8, 4, 12, 2, 10, 6, 14, 1, 9, 5, 13, 3, 11, 7, 15};
    float2 a[16];
#pragma unroll
    for (int i = 0; i < 16; ++i) a[i] = v[br[i]];
#pragma unroll
    for (int g = 0; g < 16; g += 2) {
        float2 t = a[g + 1];
        a[g + 1] = csub(a[g], t);
        a[g] = cadd(a[g], t);
    }
#pragma unroll
    for (int g = 0; g < 16; g += 4) {
        {
            float2 t = a[g + 2];
            a[g + 2] = csub(a[g], t);
            a[g] = cadd(a[g], t);
        }
        {
            float2 t = make_float2(a[g + 3].y, -a[g + 3].x);  // -i * z
            a[g + 3] = csub(a[g + 1], t);
            a[g + 1] = cadd(a[g + 1], t);
        }
    }
    {
        const float2 W4[4] = {{1.f, 0.f}, {C2, -C2}, {0.f, -1.f}, {-C2, -C2}};
#pragma unroll
        for (int g = 0; g < 16; g += 8)
#pragma unroll
            for (int j = 0; j < 4; ++j) {
                float2 t = cmul(W4[j], a[g + 4 + j]);
                a[g + 4 + j] = csub(a[g + j], t);
                a[g + j] = cadd(a[g + j], t);
            }
    }
    {
        const float2 W8[8] = {{1.f, 0.f}, {C1, -S1}, {C2, -C2}, {S1, -C1},
                              {0.f, -1.f}, {-S1, -C1}, {-C2, -C2}, {-C1, -S1}};
#pragma unroll
        for (int j = 0; j < 8; ++j) {
            float2 t = cmul(W8[j], a[8 + j]);
            a[8 + j] = csub(a[j], t);
            a[j] = cadd(a[j], t);
        }
    }
#pragma unroll
    for (int i = 0; i < 16; ++i) v[i] = a[i];
}

// ---------------- K0: transpose x[B,T,C] fp32 -> xtbf[B,C,T] bf16; also zero amps ----
__global__ void transpose_cvt_kernel(const float* __restrict__ x,
                                     unsigned short* __restrict__ xtbf,
                                     float* __restrict__ amps) {
    __shared__ float tile[64][65];
    const int b = blockIdx.y;
    const int t0 = blockIdx.x * 64;
    const int lane = threadIdx.x & 63;
    const int w = threadIdx.x >> 6;  // 0..3
    // distributed zeroing of amps (fence-free: stream order makes it visible to fft)
    {
        const int blin = blockIdx.y * (T_LEN / 64) + blockIdx.x;  // 0..4095
        if (threadIdx.x < 34) {
            int idx = blin * 34 + threadIdx.x;
            if (idx < B_N * NBINS) amps[idx] = 0.f;
        }
    }
    const float* xb = x + (size_t)b * T_LEN * C_CH;
#pragma unroll
    for (int i = 0; i < 16; ++i) {
        int r = w * 16 + i;  // t within tile
        tile[r][lane] = xb[(size_t)(t0 + r) * C_CH + lane];
    }
    __syncthreads();
    const int half = lane >> 5;     // 0..1
    const int tc = (lane & 31) * 2; // t-pair within tile
#pragma unroll
    for (int it = 0; it < 8; ++it) {
        int c = it * 8 + w * 2 + half;
        float v0 = tile[tc][c];
        float v1 = tile[tc + 1][c];
        unsigned int o = (unsigned int)f2bf(v0) | ((unsigned int)f2bf(v1) << 16);
        unsigned int* dst = (unsigned int*)(xtbf + ((size_t)b * C_CH + c) * T_LEN + t0);
        dst[lane & 31] = o;
    }
}

// ---------------- K1: radix-16 4096-pt complex FFT + |rfft| atomicAdd accumulate -------
// In-place stages; stage1->stage2 exchange is wave-local (16-thread r-groups).
// MODE 0: bf16 xtbf[B,C,T] coalesced; MODE 1: fp32 x[B,T,C] strided (fallback).
template <int MODE>
__global__ void fft_amp_kernel(const void* __restrict__ srcv, float* __restrict__ amps) {
    __shared__ float2 Z[ZSZ];  // ~33 KB padded
    const int pair = blockIdx.x;  // 0..31
    const int b = blockIdx.y;
    const int tid = threadIdx.x;

    if (MODE == 0) {
        const unsigned short* r0 =
            (const unsigned short*)srcv + ((size_t)b * C_CH + pair * 2) * T_LEN;
        const unsigned short* r1 = r0 + T_LEN;
#pragma unroll
        for (int k = 0; k < 2; ++k) {
            int t0 = k * 2048 + tid * 8;
            uint4 u0 = *(const uint4*)(r0 + t0);
            uint4 u1 = *(const uint4*)(r1 + t0);
            unsigned int a[4] = {u0.x, u0.y, u0.z, u0.w};
            unsigned int c[4] = {u1.x, u1.y, u1.z, u1.w};
#pragma unroll
            for (int j = 0; j < 4; ++j) {
                Z[PIDX(t0 + 2 * j)] = make_float2(__uint_as_float(a[j] << 16),
                                                  __uint_as_float(c[j] << 16));
                Z[PIDX(t0 + 2 * j + 1)] = make_float2(__uint_as_float(a[j] & 0xFFFF0000u),
                                                      __uint_as_float(c[j] & 0xFFFF0000u));
            }
        }
    } else {
        const float* x = (const float*)srcv;
        const int c0 = pair * 2;
        for (int t = tid; t < T_LEN; t += 256)
            Z[PIDX(t)] = *(const float2*)(x + ((size_t)b * T_LEN + t) * C_CH + c0);
    }
    __syncthreads();

    // ---- stage 0: n1 = tid; DFT16 over n2, twiddle w4096^(n1 r); in-place per-thread
    {
        float2 v[16];
#pragma unroll
        for (int t = 0; t < 16; ++t) v[t] = Z[PIDX(tid + 256 * t)];
        dft16(v);
        float s, c;
        __sincosf(-(float)tid * 1.5339807878856412e-3f, &s, &c);  // -2pi/4096 * n1
        float2 w1 = make_float2(c, s), w = w1;
#pragma unroll
        for (int r = 1; r < 16; ++r) {
            v[r] = cmul(v[r], w);
            w = cmul(w, w1);
        }
#pragma unroll
        for (int r = 0; r < 16; ++r) Z[PIDX(256 * r + tid)] = v[r];
    }
    __syncthreads();

    // ---- stage 1: thread (r,mu); DFT16 over nu; twiddle w256^(mu rho); in-place
    {
        const int r = tid >> 4, mu = tid & 15;
        float2 v[16];
#pragma unroll
        for (int nu = 0; nu < 16; ++nu) v[nu] = Z[PIDX(256 * r + mu + 16 * nu)];
        dft16(v);
        float s, c;
        __sincosf(-(float)mu * 2.4543692606170259e-2f, &s, &c);  // -2pi/256 * mu
        float2 w1 = make_float2(c, s), w = w1;
#pragma unroll
        for (int rho = 1; rho < 16; ++rho) {
            v[rho] = cmul(v[rho], w);
            w = cmul(w, w1);
        }
#pragma unroll
        for (int rho = 0; rho < 16; ++rho) Z[PIDX(256 * r + mu + 16 * rho)] = v[rho];
    }
    // stage1->stage2 exchange is within a 16-thread r-group (wave-local, DS in-order)
    __builtin_amdgcn_wave_barrier();

    // ---- stage 2: thread (r,rho); DFT16 over mu; in-place per-thread
    {
        const int r = tid >> 4, rho = tid & 15;
        float2 v[16];
#pragma unroll
        for (int mu = 0; mu < 16; ++mu) v[mu] = Z[PIDX(256 * r + mu + 16 * rho)];
        dft16(v);
#pragma unroll
        for (int mp = 0; mp < 16; ++mp) Z[PIDX(256 * r + mp + 16 * rho)] = v[mp];
    }
    __syncthreads();

    // ---- Hermitian unpack; X[k] at s(k) = 256*(k&15) + 16*((k>>4)&15) + (k>>8)
    for (int k = tid; k < NBINS; k += 256) {
        int km = (T_LEN - k) & (T_LEN - 1);
        int sk = 256 * (k & 15) + 16 * ((k >> 4) & 15) + (k >> 8);
        int sm = 256 * (km & 15) + 16 * ((km >> 4) & 15) + (km >> 8);
        float2 zk = Z[PIDX(sk)];
        float2 zm = Z[PIDX(sm)];
        float ax = 0.5f * (zk.x + zm.x);
        float ay = 0.5f * (zk.y - zm.y);
        float bx = 0.5f * (zk.y + zm.y);
        float by = -0.5f * (zk.x - zm.x);
        float amp = sqrtf(ax * ax + ay * ay) + sqrtf(bx * bx + by * by);
        atomicAdd(&amps[(size_t)b * NBINS + k], amp);
    }
}

// ---------------- K2: top-6 bins per batch (lax.top_k tie semantics) ----------------
__global__ void topk_kernel(const float* __restrict__ amps, int* __restrict__ p_int,
                            int* __restrict__ preval) {
    __shared__ float vals[NBINS];
    __shared__ float sval[256];
    __shared__ int sidx[256];
    __shared__ int sel[K2];
    const int b = blockIdx.x;
    const int tid = threadIdx.x;
    for (int k = tid; k < NBINS; k += 256) vals[k] = amps[(size_t)b * NBINS + k];
    __syncthreads();
    for (int pass = 0; pass < K2; ++pass) {
        float bv = -INFINITY;
        int bi = NBINS;
        for (int k = tid; k < NBINS; k += 256) {
            float v = vals[k];
            if (v > bv || (v == bv && k < bi)) { bv = v; bi = k; }
        }
        sval[tid] = bv;
        sidx[tid] = bi;
        __syncthreads();
        for (int off = 128; off > 0; off >>= 1) {
            if (tid < off) {
                float ov = sval[tid + off];
                int oi = sidx[tid + off];
                if (ov > sval[tid] || (ov == sval[tid] && oi < sidx[tid])) {
                    sval[tid] = ov;
                    sidx[tid] = oi;
                }
            }
            __syncthreads();
        }
        if (tid == 0) {
            sel[pass] = sidx[0];
            vals[sidx[0]] = -INFINITY;
        }
        __syncthreads();
    }
    if (tid < K2) {
        int idx = sel[tid];
        float pf = (float)T_LEN / (float)(idx + 1);
        int ir = (pf >= 2.0f) && (pf <= (float)(T_LEN / 2));
        float pff = floorf(pf);
        int iri = (pff >= 2.0f) && (pff <= (float)(T_LEN / 2));
        int pi = (int)pff;
        pi = pi < 2 ? 2 : (pi > T_LEN / 2 ? T_LEN / 2 : pi);
        p_int[b * K2 + tid] = pi;
        preval[b * K2 + tid] = ir && iri;
    }
}

// ---------------- K3a: r[t],q[t] from xtbf[B,C,T] — thread per t, batched loads -------
__global__ void rq_kernel(const unsigned short* __restrict__ xtbf,
                          const int* __restrict__ p_int, float* __restrict__ r_ws,
                          float* __restrict__ q_ws) {
    const int b = blockIdx.y;
    const int t = blockIdx.x * 64 + threadIdx.x;
    const unsigned short* xb = xtbf + (size_t)b * C_CH * T_LEN;

    int tpc[K2];
    float m[K2];
#pragma unroll
    for (int j = 0; j < K2; ++j) {
        int tp = t + p_int[b * K2 + j];  // wave-uniform p -> scalar load
        m[j] = (tp < T_LEN) ? 1.f : 0.f;
        tpc[j] = (tp < T_LEN) ? tp : (T_LEN - 1);
    }

    float qacc = 0.f;
    float racc[K2] = {0.f, 0.f, 0.f, 0.f, 0.f, 0.f};
    for (int cc = 0; cc < C_CH; cc += 8) {
        float a[8];
        float bv[K2][8];
#pragma unroll
        for (int k = 0; k < 8; ++k) a[k] = bf2f(xb[(size_t)(cc + k) * T_LEN + t]);
#pragma unroll
        for (int j = 0; j < K2; ++j)
#pragma unroll
            for (int k = 0; k < 8; ++k)
                bv[j][k] = bf2f(xb[(size_t)(cc + k) * T_LEN + tpc[j]]);
#pragma unroll
        for (int k = 0; k < 8; ++k) {
            qacc += a[k] * a[k];
#pragma unroll
            for (int j = 0; j < K2; ++j) racc[j] += a[k] * bv[j][k];
        }
    }
    q_ws[(size_t)b * T_LEN + t] = qacc;
#pragma unroll
    for (int j = 0; j < K2; ++j)
        r_ws[((size_t)b * K2 + j) * T_LEN + t] = racc[j] * m[j];
}

// ---------------- fused double scan: r and q share one barrier sequence ----------------
__device__ __forceinline__ void block_scan2_4096(float* a, float* b, float* tsa, float* tsb,
                                                 int tid) {
    float la[16], lb[16];
    const int base = tid * 16;
    float sa = 0.f, sb = 0.f;
#pragma unroll
    for (int i = 0; i < 16; ++i) {
        sa += a[base + i];
        la[i] = sa;
        sb += b[base + i];
        lb[i] = sb;
    }
    tsa[tid] = sa;
    tsb[tid] = sb;
    __syncthreads();
    for (int off = 1; off < 256; off <<= 1) {
        float va = (tid >= off) ? tsa[tid - off] : 0.f;
        float vb = (tid >= off) ? tsb[tid - off] : 0.f;
        __syncthreads();
        tsa[tid] += va;
        tsb[tid] += vb;
        __syncthreads();
    }
    float offa = tsa[tid] - sa;
    float offb = tsb[tid] - sb;
#pragma unroll
    for (int i = 0; i < 16; ++i) {
        a[base + i] = offa + la[i];
        b[base + i] = offb + lb[i];
    }
    __syncthreads();
}

// single-array scan (fallback autocorr path)
__device__ __forceinline__ void block_scan_4096(float* a, float* tsum, int tid) {
    float loc[16];
    const int base = tid * 16;
    float s = 0.f;
#pragma unroll
    for (int i = 0; i < 16; ++i) {
        s += a[base + i];
        loc[i] = s;
    }
    tsum[tid] = s;
    __syncthreads();
    for (int off = 1; off < 256; off <<= 1) {
        float v = (tid >= off) ? tsum[tid - off] : 0.f;
        __syncthreads();
        tsum[tid] += v;
        __syncthreads();
    }
    float offs = tsum[tid] - s;
#pragma unroll
    for (int i = 0; i < 16; ++i) a[base + i] = offs + loc[i];
    __syncthreads();
}

// ---------------- K3b: fused scan + segment cosines ----------------
__global__ void score_kernel(const float* __restrict__ r_ws, const float* __restrict__ q_ws,
                             const int* __restrict__ p_int, float* __restrict__ scores) {
    __shared__ float r_s[T_LEN];
    __shared__ float q_s[T_LEN];
    __shared__ float tsum[512];
    const int cand = blockIdx.x;
    const int b = blockIdx.y;
    const int tid = threadIdx.x;
    const int p = p_int[b * K2 + cand];
    const float4* rsrc = (const float4*)(r_ws + ((size_t)b * K2 + cand) * T_LEN);
    const float4* qsrc = (const float4*)(q_ws + (size_t)b * T_LEN);
    for (int i = tid; i < T_LEN / 4; i += 256) {
        ((float4*)r_s)[i] = rsrc[i];
        ((float4*)q_s)[i] = qsrc[i];
    }
    __syncthreads();
    block_scan2_4096(r_s, q_s, tsum, tsum + 256, tid);
    const int nper = T_LEN / p;
    float part = 0.f;
    for (int i = tid; i < nper - 1; i += 256) {
        int s0 = i * p;
        int e = s0 + p;
        int e2 = e + p;
        float crs = s0 ? r_s[s0 - 1] : 0.f;
        float dots = r_s[e - 1] - crs;
        float cqs = s0 ? q_s[s0 - 1] : 0.f;
        float qa = q_s[e - 1] - cqs;
        float qb = q_s[e2 - 1] - q_s[e - 1];
        float na = sqrtf(fmaxf(qa, 0.f));
        float nb = sqrtf(fmaxf(qb, 0.f));
        part += dots / fmaxf(na * nb, 1e-8f);
    }
    tsum[tid] = part;
    __syncthreads();
    for (int off = 128; off > 0; off >>= 1) {
        if (tid < off) tsum[tid] += tsum[tid + off];
        __syncthreads();
    }
    if (tid == 0) scores[b * K2 + cand] = tsum[0] / (float)(nper - 1);
}

// ---------------- fallback fused autocorr (tiny-ws path) ----------------
__global__ void autocorr_kernel(const float* __restrict__ x, const int* __restrict__ p_int,
                                float* __restrict__ scores) {
    __shared__ float r_s[T_LEN];
    __shared__ float q_s[T_LEN];
    __shared__ float tsum[256];
    const int cand = blockIdx.x;
    const int b = blockIdx.y;
    const int tid = threadIdx.x;
    const int p = p_int[b * K2 + cand];
    const float* xb = x + (size_t)b * T_LEN * C_CH;
    for (int t = tid; t < T_LEN; t += 256) {
        const float4* row = (const float4*)(xb + (size_t)t * C_CH);
        float q = 0.f, r = 0.f;
        if (t + p < T_LEN) {
            const float4* row2 = (const float4*)(xb + (size_t)(t + p) * C_CH);
#pragma unroll
            for (int i = 0; i < 16; ++i) {
                float4 a = row[i], c = row2[i];
                r += a.x * c.x + a.y * c.y + a.z * c.z + a.w * c.w;
                q += a.x * a.x + a.y * a.y + a.z * a.z + a.w * a.w;
            }
        } else {
#pragma unroll
            for (int i = 0; i < 16; ++i) {
                float4 a = row[i];
                q += a.x * a.x + a.y * a.y + a.z * a.z + a.w * a.w;
            }
        }
        r_s[t] = r;
        q_s[t] = q;
    }
    __syncthreads();
    block_scan_4096(r_s, tsum, tid);
    block_scan_4096(q_s, tsum, tid);
    const int nper = T_LEN / p;
    float part = 0.f;
    for (int i = tid; i < nper - 1; i += 256) {
        int s0 = i * p;
        int e = s0 + p;
        int e2 = e + p;
        float crs = s0 ? r_s[s0 - 1] : 0.f;
        float dots = r_s[e - 1] - crs;
        float cqs = s0 ? q_s[s0 - 1] : 0.f;
        float qa = q_s[e - 1] - cqs;
        float qb = q_s[e2 - 1] - q_s[e - 1];
        float na = sqrtf(fmaxf(qa, 0.f));
        float nb = sqrtf(fmaxf(qb, 0.f));
        part += dots / fmaxf(na * nb, 1e-8f);
    }
    tsum[tid] = part;
    __syncthreads();
    for (int off = 128; off > 0; off >>= 1) {
        if (tid < off) tsum[tid] += tsum[tid + off];
        __syncthreads();
    }
    if (tid == 0) scores[b * K2 + cand] = tsum[0] / (float)(nper - 1);
}

// ---------------- K4: final selection + fallback fill ----------------
__global__ void select_kernel(const int* __restrict__ p_int, const int* __restrict__ preval,
                              const float* __restrict__ scores, float* __restrict__ out) {
    const int b = threadIdx.x;
    if (b >= B_N) return;
    int sel[TOPK];
    int cnt = 0;
    for (int j = 0; j < K2; ++j) {
        if (preval[b * K2 + j] && scores[b * K2 + j] > THRESH_V) {
            if (cnt < TOPK) sel[cnt] = p_int[b * K2 + j];
            cnt++;
        }
    }
    if (cnt > TOPK) cnt = TOPK;
    int add[4];
    int nadd = 0;
    int cms[4] = {T_LEN / 4, T_LEN / 3, T_LEN / 2, (int)((float)T_LEN / 1.5f)};
    for (int i = 0; i < 4; ++i)
        if (cms[i] >= 2 && cms[i] <= T_LEN / 2) add[nadd++] = cms[i];
    for (int j = 0; j < TOPK; ++j) {
        float pv, wv;
        if (j < cnt) {
            pv = (float)sel[j];
            wv = 1.0f;
        } else {
            int a = j - cnt;
            if (a > nadd - 1) a = nadd - 1;
            pv = (float)add[a];
            wv = 0.5f;
        }
        out[b * TOPK + j] = pv;
        out[B_N * TOPK + b * TOPK + j] = wv;
    }
}

static size_t align256(size_t v) { return (v + 255) & ~(size_t)255; }

extern "C" void kernel_launch(void* const* d_in, const int* in_sizes, int n_in,
                              void* d_out, int out_size, void* d_ws, size_t ws_size,
                              hipStream_t stream) {
    const float* x = (const float*)d_in[0];
    float* out = (float*)d_out;
    char* ws = (char*)d_ws;

    const size_t amps_b = align256((size_t)B_N * NBINS * sizeof(float));        // ~0.5 MB
    const size_t int_b = align256((size_t)B_N * K2 * sizeof(int));
    const size_t r_b = align256((size_t)B_N * K2 * T_LEN * sizeof(float));      // 6.3 MB
    const size_t q_b = align256((size_t)B_N * T_LEN * sizeof(float));           // 1 MB
    const size_t xtbf_b = align256((size_t)B_N * T_LEN * C_CH * sizeof(short)); // 32 MB

    size_t off = 0;
    float* amps = (float*)(ws + off); off += amps_b;
    int* p_int = (int*)(ws + off); off += int_b;
    int* preval = (int*)(ws + off); off += int_b;
    float* scores = (float*)(ws + off); off += int_b;
    float* r_ws = (float*)(ws + off); off += r_b;
    float* q_ws = (float*)(ws + off); off += q_b;
    unsigned short* xtbf = (unsigned short*)(ws + off); off += xtbf_b;
    const size_t full_need = off;

    if (ws_size >= full_need) {
        // 6 nodes, no memsets: transpose(+zero amps) -> fft -> topk -> rq -> score -> select
        transpose_cvt_kernel<<<dim3(T_LEN / 64, B_N), 256, 0, stream>>>(x, xtbf, amps);
        fft_amp_kernel<0><<<dim3(C_CH / 2, B_N), 256, 0, stream>>>(xtbf, amps);
        topk_kernel<<<B_N, 256, 0, stream>>>(amps, p_int, preval);
        rq_kernel<<<dim3(T_LEN / 64, B_N), 64, 0, stream>>>(xtbf, p_int, r_ws, q_ws);
        score_kernel<<<dim3(K2, B_N), 256, 0, stream>>>(r_ws, q_ws, p_int, scores);
        select_kernel<<<1, 64, 0, stream>>>(p_int, preval, scores, out);
    } else {
        hipMemsetAsync(amps, 0, amps_b, stream);
        fft_amp_kernel<1><<<dim3(C_CH / 2, B_N), 256, 0, stream>>>(x, amps);
        topk_kernel<<<B_N, 256, 0, stream>>>(amps, p_int, preval);
        autocorr_kernel<<<dim3(K2, B_N), 256, 0, stream>>>(x, p_int, scores);
        select_kernel<<<1, 64, 0, stream>>>(p_int, preval, scores, out);
    }
}

// Round 9
// 166.771 us; speedup vs baseline: 2.5847x; 1.0104x over previous
//
#include <hip/hip_runtime.h>
#include <math.h>

#define T_LEN 4096
#define C_CH 64
#define B_N 64
#define NBINS 2049   // T/2 + 1
#define K2 6         // 2*TOP_K
#define TOPK 3
#define THRESH_V 0.2f

// LDS pad: one extra slot per 32 -> breaks power-of-2 stride bank aliasing
#define PIDX(i) ((i) + ((i) >> 5))
#define ZSZ (T_LEN + (T_LEN >> 5))

__device__ __forceinline__ unsigned short f2bf(float v) {
    unsigned int u = __float_as_uint(v);
    u += 0x7FFFu + ((u >> 16) & 1u);  // RNE
    return (unsigned short)(u >> 16);
}
__device__ __forceinline__ float bf2f(unsigned short h) {
    return __uint_as_float(((unsigned int)h) << 16);
}
// packed bf16 complex (re in low 16, im in high 16) <-> float2
__device__ __forceinline__ float2 zld(unsigned int v) {
    return make_float2(__uint_as_float(v << 16), __uint_as_float(v & 0xFFFF0000u));
}
__device__ __forceinline__ unsigned int zst(float2 z) {
    return (unsigned int)f2bf(z.x) | ((unsigned int)f2bf(z.y) << 16);
}

// ---------------- complex helpers ----------------
__device__ __forceinline__ float2 cmul(float2 a, float2 b) {
    return make_float2(a.x * b.x - a.y * b.y, a.x * b.y + a.y * b.x);
}
__device__ __forceinline__ float2 cadd(float2 a, float2 b) { return make_float2(a.x + b.x, a.y + b.y); }
__device__ __forceinline__ float2 csub(float2 a, float2 b) { return make_float2(a.x - b.x, a.y - b.y); }

// 16-point forward DFT in registers (natural in, natural out), radix-2 DIT.
__device__ __forceinline__ void dft16(float2* v) {
    const float C2 = 0.70710678118654752f;
    const float C1 = 0.92387953251128676f;
    const float S1 = 0.38268343236508977f;
    const int br[16] = {0, 8, 4, 12, 2, 10, 6, 14, 1, 9, 5, 13, 3, 11, 7, 15};
    float2 a[16];
#pragma unroll
    for (int i = 0; i < 16; ++i) a[i] = v[br[i]];
#pragma unroll
    for (int g = 0; g < 16; g += 2) {
        float2 t = a[g + 1];
        a[g + 1] = csub(a[g], t);
        a[g] = cadd(a[g], t);
    }
#pragma unroll
    for (int g = 0; g < 16; g += 4) {
        {
            float2 t = a[g + 2];
            a[g + 2] = csub(a[g], t);
            a[g] = cadd(a[g], t);
        }
        {
            float2 t = make_float2(a[g + 3].y, -a[g + 3].x);  // -i * z
            a[g + 3] = csub(a[g + 1], t);
            a[g + 1] = cadd(a[g + 1], t);
        }
    }
    {
        const float2 W4[4] = {{1.f, 0.f}, {C2, -C2}, {0.f, -1.f}, {-C2, -C2}};
#pragma unroll
        for (int g = 0; g < 16; g += 8)
#pragma unroll
            for (int j = 0; j < 4; ++j) {
                float2 t = cmul(W4[j], a[g + 4 + j]);
                a[g + 4 + j] = csub(a[g + j], t);
                a[g + j] = cadd(a[g + j], t);
            }
    }
    {
        const float2 W8[8] = {{1.f, 0.f}, {C1, -S1}, {C2, -C2}, {S1, -C1},
                              {0.f, -1.f}, {-S1, -C1}, {-C2, -C2}, {-C1, -S1}};
#pragma unroll
        for (int j = 0; j < 8; ++j) {
            float2 t = cmul(W8[j], a[8 + j]);
            a[8 + j] = csub(a[j], t);
            a[j] = cadd(a[j], t);
        }
    }
#pragma unroll
    for (int i = 0; i < 16; ++i) v[i] = a[i];
}

// ---------------- K0: transpose x[B,T,C] fp32 -> xtbf[B,C,T] bf16; also zero amps ----
__global__ void transpose_cvt_kernel(const float* __restrict__ x,
                                     unsigned short* __restrict__ xtbf,
                                     float* __restrict__ amps) {
    __shared__ float tile[64][65];
    const int b = blockIdx.y;
    const int t0 = blockIdx.x * 64;
    const int lane = threadIdx.x & 63;
    const int w = threadIdx.x >> 6;  // 0..3
    // distributed zeroing of amps (fence-free: stream order makes it visible to fft)
    {
        const int blin = blockIdx.y * (T_LEN / 64) + blockIdx.x;  // 0..4095
        if (threadIdx.x < 34) {
            int idx = blin * 34 + threadIdx.x;
            if (idx < B_N * NBINS) amps[idx] = 0.f;
        }
    }
    const float* xb = x + (size_t)b * T_LEN * C_CH;
#pragma unroll
    for (int i = 0; i < 16; ++i) {
        int r = w * 16 + i;  // t within tile
        tile[r][lane] = xb[(size_t)(t0 + r) * C_CH + lane];
    }
    __syncthreads();
    const int half = lane >> 5;     // 0..1
    const int tc = (lane & 31) * 2; // t-pair within tile
#pragma unroll
    for (int it = 0; it < 8; ++it) {
        int c = it * 8 + w * 2 + half;
        float v0 = tile[tc][c];
        float v1 = tile[tc + 1][c];
        unsigned int o = (unsigned int)f2bf(v0) | ((unsigned int)f2bf(v1) << 16);
        unsigned int* dst = (unsigned int*)(xtbf + ((size_t)b * C_CH + c) * T_LEN + t0);
        dst[lane & 31] = o;
    }
}

// ---------------- K1: radix-16 4096-pt complex FFT, bf16-packed LDS ----------------
// In-place stages; stage1->stage2 exchange wave-local. 16.9 KB LDS -> 8 blocks/CU.
// MODE 0: bf16 xtbf[B,C,T] coalesced; MODE 1: fp32 x[B,T,C] strided (fallback).
template <int MODE>
__launch_bounds__(256, 8)
__global__ void fft_amp_kernel(const void* __restrict__ srcv, float* __restrict__ amps) {
    __shared__ unsigned int Z[ZSZ];  // packed bf16 complex, ~16.9 KB
    const int pair = blockIdx.x;  // 0..31
    const int b = blockIdx.y;
    const int tid = threadIdx.x;

    if (MODE == 0) {
        const unsigned short* r0 =
            (const unsigned short*)srcv + ((size_t)b * C_CH + pair * 2) * T_LEN;
        const unsigned short* r1 = r0 + T_LEN;
#pragma unroll
        for (int k = 0; k < 2; ++k) {
            int t0 = k * 2048 + tid * 8;
            uint4 u0 = *(const uint4*)(r0 + t0);  // 8 t's of ch0
            uint4 u1 = *(const uint4*)(r1 + t0);  // 8 t's of ch1
            unsigned int a[4] = {u0.x, u0.y, u0.z, u0.w};
            unsigned int c[4] = {u1.x, u1.y, u1.z, u1.w};
#pragma unroll
            for (int j = 0; j < 4; ++j) {
                Z[PIDX(t0 + 2 * j)] = (a[j] & 0xFFFFu) | (c[j] << 16);
                Z[PIDX(t0 + 2 * j + 1)] = (a[j] >> 16) | (c[j] & 0xFFFF0000u);
            }
        }
    } else {
        const float* x = (const float*)srcv;
        const int c0 = pair * 2;
        for (int t = tid; t < T_LEN; t += 256) {
            float2 v = *(const float2*)(x + ((size_t)b * T_LEN + t) * C_CH + c0);
            Z[PIDX(t)] = zst(v);
        }
    }
    __syncthreads();

    // ---- stage 0: n1 = tid; DFT16 over n2, twiddle w4096^(n1 r); in-place per-thread
    {
        float2 v[16];
#pragma unroll
        for (int t = 0; t < 16; ++t) v[t] = zld(Z[PIDX(tid + 256 * t)]);
        dft16(v);
        float s, c;
        __sincosf(-(float)tid * 1.5339807878856412e-3f, &s, &c);  // -2pi/4096 * n1
        float2 w1 = make_float2(c, s), w = w1;
#pragma unroll
        for (int r = 1; r < 16; ++r) {
            v[r] = cmul(v[r], w);
            w = cmul(w, w1);
        }
#pragma unroll
        for (int r = 0; r < 16; ++r) Z[PIDX(256 * r + tid)] = zst(v[r]);
    }
    __syncthreads();

    // ---- stage 1: thread (r,mu); DFT16 over nu; twiddle w256^(mu rho); in-place
    {
        const int r = tid >> 4, mu = tid & 15;
        float2 v[16];
#pragma unroll
        for (int nu = 0; nu < 16; ++nu) v[nu] = zld(Z[PIDX(256 * r + mu + 16 * nu)]);
        dft16(v);
        float s, c;
        __sincosf(-(float)mu * 2.4543692606170259e-2f, &s, &c);  // -2pi/256 * mu
        float2 w1 = make_float2(c, s), w = w1;
#pragma unroll
        for (int rho = 1; rho < 16; ++rho) {
            v[rho] = cmul(v[rho], w);
            w = cmul(w, w1);
        }
#pragma unroll
        for (int rho = 0; rho < 16; ++rho) Z[PIDX(256 * r + mu + 16 * rho)] = zst(v[rho]);
    }
    // stage1->stage2 exchange is within a 16-thread r-group (wave-local, DS in-order)
    __builtin_amdgcn_wave_barrier();

    // ---- stage 2: thread (r,rho); DFT16 over mu; in-place per-thread
    {
        const int r = tid >> 4, rho = tid & 15;
        float2 v[16];
#pragma unroll
        for (int mu = 0; mu < 16; ++mu) v[mu] = zld(Z[PIDX(256 * r + mu + 16 * rho)]);
        dft16(v);
#pragma unroll
        for (int mp = 0; mp < 16; ++mp) Z[PIDX(256 * r + mp + 16 * rho)] = zst(v[mp]);
    }
    __syncthreads();

    // ---- Hermitian unpack; X[k] at s(k) = 256*(k&15) + 16*((k>>4)&15) + (k>>8)
    for (int k = tid; k < NBINS; k += 256) {
        int km = (T_LEN - k) & (T_LEN - 1);
        int sk = 256 * (k & 15) + 16 * ((k >> 4) & 15) + (k >> 8);
        int sm = 256 * (km & 15) + 16 * ((km >> 4) & 15) + (km >> 8);
        float2 zk = zld(Z[PIDX(sk)]);
        float2 zm = zld(Z[PIDX(sm)]);
        float ax = 0.5f * (zk.x + zm.x);
        float ay = 0.5f * (zk.y - zm.y);
        float bx = 0.5f * (zk.y + zm.y);
        float by = -0.5f * (zk.x - zm.x);
        float amp = sqrtf(ax * ax + ay * ay) + sqrtf(bx * bx + by * by);
        atomicAdd(&amps[(size_t)b * NBINS + k], amp);
    }
}

// ---------------- K2: top-6 bins per batch (lax.top_k tie semantics); zeros counter ---
__global__ void topk_kernel(const float* __restrict__ amps, int* __restrict__ p_int,
                            int* __restrict__ preval, int* __restrict__ counter) {
    __shared__ float vals[NBINS];
    __shared__ float sval[256];
    __shared__ int sidx[256];
    __shared__ int sel[K2];
    const int b = blockIdx.x;
    const int tid = threadIdx.x;
    if (b == 0 && tid == 0) *counter = 0;  // visible to score via dispatch boundary
    for (int k = tid; k < NBINS; k += 256) vals[k] = amps[(size_t)b * NBINS + k];
    __syncthreads();
    for (int pass = 0; pass < K2; ++pass) {
        float bv = -INFINITY;
        int bi = NBINS;
        for (int k = tid; k < NBINS; k += 256) {
            float v = vals[k];
            if (v > bv || (v == bv && k < bi)) { bv = v; bi = k; }
        }
        sval[tid] = bv;
        sidx[tid] = bi;
        __syncthreads();
        for (int off = 128; off > 0; off >>= 1) {
            if (tid < off) {
                float ov = sval[tid + off];
                int oi = sidx[tid + off];
                if (ov > sval[tid] || (ov == sval[tid] && oi < sidx[tid])) {
                    sval[tid] = ov;
                    sidx[tid] = oi;
                }
            }
            __syncthreads();
        }
        if (tid == 0) {
            sel[pass] = sidx[0];
            vals[sidx[0]] = -INFINITY;
        }
        __syncthreads();
    }
    if (tid < K2) {
        int idx = sel[tid];
        float pf = (float)T_LEN / (float)(idx + 1);
        int ir = (pf >= 2.0f) && (pf <= (float)(T_LEN / 2));
        float pff = floorf(pf);
        int iri = (pff >= 2.0f) && (pff <= (float)(T_LEN / 2));
        int pi = (int)pff;
        pi = pi < 2 ? 2 : (pi > T_LEN / 2 ? T_LEN / 2 : pi);
        p_int[b * K2 + tid] = pi;
        preval[b * K2 + tid] = ir && iri;
    }
}

// ---------------- K3a: r[t],q[t] from xtbf[B,C,T] — thread per t, batched loads -------
__global__ void rq_kernel(const unsigned short* __restrict__ xtbf,
                          const int* __restrict__ p_int, float* __restrict__ r_ws,
                          float* __restrict__ q_ws) {
    const int b = blockIdx.y;
    const int t = blockIdx.x * 64 + threadIdx.x;
    const unsigned short* xb = xtbf + (size_t)b * C_CH * T_LEN;

    int tpc[K2];
    float m[K2];
#pragma unroll
    for (int j = 0; j < K2; ++j) {
        int tp = t + p_int[b * K2 + j];  // wave-uniform p -> scalar load
        m[j] = (tp < T_LEN) ? 1.f : 0.f;
        tpc[j] = (tp < T_LEN) ? tp : (T_LEN - 1);
    }

    float qacc = 0.f;
    float racc[K2] = {0.f, 0.f, 0.f, 0.f, 0.f, 0.f};
    for (int cc = 0; cc < C_CH; cc += 8) {
        float a[8];
        float bv[K2][8];
#pragma unroll
        for (int k = 0; k < 8; ++k) a[k] = bf2f(xb[(size_t)(cc + k) * T_LEN + t]);
#pragma unroll
        for (int j = 0; j < K2; ++j)
#pragma unroll
            for (int k = 0; k < 8; ++k)
                bv[j][k] = bf2f(xb[(size_t)(cc + k) * T_LEN + tpc[j]]);
#pragma unroll
        for (int k = 0; k < 8; ++k) {
            qacc += a[k] * a[k];
#pragma unroll
            for (int j = 0; j < K2; ++j) racc[j] += a[k] * bv[j][k];
        }
    }
    q_ws[(size_t)b * T_LEN + t] = qacc;
#pragma unroll
    for (int j = 0; j < K2; ++j)
        r_ws[((size_t)b * K2 + j) * T_LEN + t] = racc[j] * m[j];
}

// ---------------- fused double scan: r and q share one barrier sequence ----------------
__device__ __forceinline__ void block_scan2_4096(float* a, float* b, float* tsa, float* tsb,
                                                 int tid) {
    float la[16], lb[16];
    const int base = tid * 16;
    float sa = 0.f, sb = 0.f;
#pragma unroll
    for (int i = 0; i < 16; ++i) {
        sa += a[base + i];
        la[i] = sa;
        sb += b[base + i];
        lb[i] = sb;
    }
    tsa[tid] = sa;
    tsb[tid] = sb;
    __syncthreads();
    for (int off = 1; off < 256; off <<= 1) {
        float va = (tid >= off) ? tsa[tid - off] : 0.f;
        float vb = (tid >= off) ? tsb[tid - off] : 0.f;
        __syncthreads();
        tsa[tid] += va;
        tsb[tid] += vb;
        __syncthreads();
    }
    float offa = tsa[tid] - sa;
    float offb = tsb[tid] - sb;
#pragma unroll
    for (int i = 0; i < 16; ++i) {
        a[base + i] = offa + la[i];
        b[base + i] = offb + lb[i];
    }
    __syncthreads();
}

// single-array scan (fallback autocorr path)
__device__ __forceinline__ void block_scan_4096(float* a, float* tsum, int tid) {
    float loc[16];
    const int base = tid * 16;
    float s = 0.f;
#pragma unroll
    for (int i = 0; i < 16; ++i) {
        s += a[base + i];
        loc[i] = s;
    }
    tsum[tid] = s;
    __syncthreads();
    for (int off = 1; off < 256; off <<= 1) {
        float v = (tid >= off) ? tsum[tid - off] : 0.f;
        __syncthreads();
        tsum[tid] += v;
        __syncthreads();
    }
    float offs = tsum[tid] - s;
#pragma unroll
    for (int i = 0; i < 16; ++i) a[base + i] = offs + loc[i];
    __syncthreads();
}

// ---------------- select helpers ----------------
__device__ __forceinline__ void select_core(int b, const int* p_int, const int* preval,
                                            const float* sc6, float* out) {
    int sel[TOPK];
    int cnt = 0;
    for (int j = 0; j < K2; ++j) {
        if (preval[b * K2 + j] && sc6[j] > THRESH_V) {
            if (cnt < TOPK) sel[cnt] = p_int[b * K2 + j];
            cnt++;
        }
    }
    if (cnt > TOPK) cnt = TOPK;
    int add[4];
    int nadd = 0;
    int cms[4] = {T_LEN / 4, T_LEN / 3, T_LEN / 2, (int)((float)T_LEN / 1.5f)};
    for (int i = 0; i < 4; ++i)
        if (cms[i] >= 2 && cms[i] <= T_LEN / 2) add[nadd++] = cms[i];
    for (int j = 0; j < TOPK; ++j) {
        float pv, wv;
        if (j < cnt) {
            pv = (float)sel[j];
            wv = 1.0f;
        } else {
            int a = j - cnt;
            if (a > nadd - 1) a = nadd - 1;
            pv = (float)add[a];
            wv = 0.5f;
        }
        out[b * TOPK + j] = pv;
        out[B_N * TOPK + b * TOPK + j] = wv;
    }
}

// ---------------- K3b: fused scan + segment cosines + (last block) select ------------
__global__ void score_kernel(const float* __restrict__ r_ws, const float* __restrict__ q_ws,
                             const int* __restrict__ p_int, const int* __restrict__ preval,
                             float* __restrict__ scores, int* __restrict__ counter,
                             float* __restrict__ out) {
    __shared__ float r_s[T_LEN];
    __shared__ float q_s[T_LEN];
    __shared__ float tsum[512];
    __shared__ int lastflag;
    const int cand = blockIdx.x;
    const int b = blockIdx.y;
    const int tid = threadIdx.x;
    const int p = p_int[b * K2 + cand];
    const float4* rsrc = (const float4*)(r_ws + ((size_t)b * K2 + cand) * T_LEN);
    const float4* qsrc = (const float4*)(q_ws + (size_t)b * T_LEN);
    for (int i = tid; i < T_LEN / 4; i += 256) {
        ((float4*)r_s)[i] = rsrc[i];
        ((float4*)q_s)[i] = qsrc[i];
    }
    __syncthreads();
    block_scan2_4096(r_s, q_s, tsum, tsum + 256, tid);
    const int nper = T_LEN / p;
    float part = 0.f;
    for (int i = tid; i < nper - 1; i += 256) {
        int s0 = i * p;
        int e = s0 + p;
        int e2 = e + p;
        float crs = s0 ? r_s[s0 - 1] : 0.f;
        float dots = r_s[e - 1] - crs;
        float cqs = s0 ? q_s[s0 - 1] : 0.f;
        float qa = q_s[e - 1] - cqs;
        float qb = q_s[e2 - 1] - q_s[e - 1];
        float na = sqrtf(fmaxf(qa, 0.f));
        float nb = sqrtf(fmaxf(qb, 0.f));
        part += dots / fmaxf(na * nb, 1e-8f);
    }
    tsum[tid] = part;
    __syncthreads();
    for (int off = 128; off > 0; off >>= 1) {
        if (tid < off) tsum[tid] += tsum[tid + off];
        __syncthreads();
    }
    if (tid == 0) {
        float sc = tsum[0] / (float)(nper - 1);
        // device-scope atomic store (coherent point), NO fence
        float old = atomicExch(&scores[b * K2 + cand], sc);
        // order counter-add after the exch completes: consume exch result in asm
        int inc;
        asm volatile("v_mov_b32 %0, 1" : "=v"(inc) : "v"(old));
        int prev = atomicAdd(counter, inc);
        lastflag = (prev == K2 * B_N - 1) ? 1 : 0;
    }
    __syncthreads();
    if (lastflag && tid < B_N) {
        float sc6[K2];
#pragma unroll
        for (int j = 0; j < K2; ++j)
            sc6[j] = atomicAdd(&scores[tid * K2 + j], 0.0f);  // coherent read
        select_core(tid, p_int, preval, sc6, out);
    }
}

// ---------------- fallback fused autocorr (tiny-ws path) ----------------
__global__ void autocorr_kernel(const float* __restrict__ x, const int* __restrict__ p_int,
                                float* __restrict__ scores) {
    __shared__ float r_s[T_LEN];
    __shared__ float q_s[T_LEN];
    __shared__ float tsum[256];
    const int cand = blockIdx.x;
    const int b = blockIdx.y;
    const int tid = threadIdx.x;
    const int p = p_int[b * K2 + cand];
    const float* xb = x + (size_t)b * T_LEN * C_CH;
    for (int t = tid; t < T_LEN; t += 256) {
        const float4* row = (const float4*)(xb + (size_t)t * C_CH);
        float q = 0.f, r = 0.f;
        if (t + p < T_LEN) {
            const float4* row2 = (const float4*)(xb + (size_t)(t + p) * C_CH);
#pragma unroll
            for (int i = 0; i < 16; ++i) {
                float4 a = row[i], c = row2[i];
                r += a.x * c.x + a.y * c.y + a.z * c.z + a.w * c.w;
                q += a.x * a.x + a.y * a.y + a.z * a.z + a.w * a.w;
            }
        } else {
#pragma unroll
            for (int i = 0; i < 16; ++i) {
                float4 a = row[i];
                q += a.x * a.x + a.y * a.y + a.z * a.z + a.w * a.w;
            }
        }
        r_s[t] = r;
        q_s[t] = q;
    }
    __syncthreads();
    block_scan_4096(r_s, tsum, tid);
    block_scan_4096(q_s, tsum, tid);
    const int nper = T_LEN / p;
    float part = 0.f;
    for (int i = tid; i < nper - 1; i += 256) {
        int s0 = i * p;
        int e = s0 + p;
        int e2 = e + p;
        float crs = s0 ? r_s[s0 - 1] : 0.f;
        float dots = r_s[e - 1] - crs;
        float cqs = s0 ? q_s[s0 - 1] : 0.f;
        float qa = q_s[e - 1] - cqs;
        float qb = q_s[e2 - 1] - q_s[e - 1];
        float na = sqrtf(fmaxf(qa, 0.f));
        float nb = sqrtf(fmaxf(qb, 0.f));
        part += dots / fmaxf(na * nb, 1e-8f);
    }
    tsum[tid] = part;
    __syncthreads();
    for (int off = 128; off > 0; off >>= 1) {
        if (tid < off) tsum[tid] += tsum[tid + off];
        __syncthreads();
    }
    if (tid == 0) scores[b * K2 + cand] = tsum[0] / (float)(nper - 1);
}

// ---------------- K4: standalone select (fallback path only) ----------------
__global__ void select_kernel(const int* __restrict__ p_int, const int* __restrict__ preval,
                              const float* __restrict__ scores, float* __restrict__ out) {
    const int b = threadIdx.x;
    if (b >= B_N) return;
    float sc6[K2];
    for (int j = 0; j < K2; ++j) sc6[j] = scores[b * K2 + j];
    select_core(b, p_int, preval, sc6, out);
}

static size_t align256(size_t v) { return (v + 255) & ~(size_t)255; }

extern "C" void kernel_launch(void* const* d_in, const int* in_sizes, int n_in,
                              void* d_out, int out_size, void* d_ws, size_t ws_size,
                              hipStream_t stream) {
    const float* x = (const float*)d_in[0];
    float* out = (float*)d_out;
    char* ws = (char*)d_ws;

    const size_t amps_b = align256((size_t)B_N * NBINS * sizeof(float));        // ~0.5 MB
    const size_t int_b = align256((size_t)B_N * K2 * sizeof(int));
    const size_t r_b = align256((size_t)B_N * K2 * T_LEN * sizeof(float));      // 6.3 MB
    const size_t q_b = align256((size_t)B_N * T_LEN * sizeof(float));           // 1 MB
    const size_t xtbf_b = align256((size_t)B_N * T_LEN * C_CH * sizeof(short)); // 32 MB

    size_t off = 0;
    float* amps = (float*)(ws + off); off += amps_b;
    int* p_int = (int*)(ws + off); off += int_b;
    int* preval = (int*)(ws + off); off += int_b;
    float* scores = (float*)(ws + off); off += int_b;
    int* counter = (int*)(ws + off); off += 256;
    float* r_ws = (float*)(ws + off); off += r_b;
    float* q_ws = (float*)(ws + off); off += q_b;
    unsigned short* xtbf = (unsigned short*)(ws + off); off += xtbf_b;
    const size_t full_need = off;

    if (ws_size >= full_need) {
        // 5 nodes: transpose(+zero amps) -> fft -> topk(+zero counter) -> rq -> score(+select)
        transpose_cvt_kernel<<<dim3(T_LEN / 64, B_N), 256, 0, stream>>>(x, xtbf, amps);
        fft_amp_kernel<0><<<dim3(C_CH / 2, B_N), 256, 0, stream>>>(xtbf, amps);
        topk_kernel<<<B_N, 256, 0, stream>>>(amps, p_int, preval, counter);
        rq_kernel<<<dim3(T_LEN / 64, B_N), 64, 0, stream>>>(xtbf, p_int, r_ws, q_ws);
        score_kernel<<<dim3(K2, B_N), 256, 0, stream>>>(r_ws, q_ws, p_int, preval, scores,
                                                        counter, out);
    } else {
        hipMemsetAsync(amps, 0, amps_b, stream);
        fft_amp_kernel<1><<<dim3(C_CH / 2, B_N), 256, 0, stream>>>(x, amps);
        topk_kernel<<<B_N, 256, 0, stream>>>(amps, p_int, preval, counter);
        autocorr_kernel<<<dim3(K2, B_N), 256, 0, stream>>>(x, p_int, scores);
        select_kernel<<<1, 64, 0, stream>>>(p_int, preval, scores, out);
    }
}